// Round 2
// baseline (15431.351 us; speedup 1.0000x reference)
//
#include <hip/hip_runtime.h>
#include <cstdint>
#include <cstddef>

// ---------------------------------------------------------------------------
// GraphUNetSmall: fp32 graph U-Net via atomic scatter-add kernels.
// All intermediate conv outputs are stored PRE-activation (bias included via
// init); consumers apply ReLU at gather time. scatter_w outputs are raw sums.
//
// R1 fix: edge-attr pointers were read from the edge-INDEX buffer (d_in[i])
// instead of d_in[i+1] — int bit patterns as fp32 are denormals -> FTZ -> 0,
// which zeroed the entire network (error == max|ref| exactly).
// ---------------------------------------------------------------------------

#define DEV __device__ __forceinline__

static constexpr int NCc = 1000000;
static constexpr int NFc = 1500000;
static constexpr int N0c = 500000;
static constexpr int N1c = 125000;
static constexpr int N2c = 31250;
static constexpr int N3c = 7813;
static constexpr int N4c = 1954;

template<int F, bool R>
DEV void load_feats(const float* __restrict__ p, float* r) {
    if constexpr (F == 2) {
        float2 v = *reinterpret_cast<const float2*>(p);
        r[0] = R ? fmaxf(v.x, 0.f) : v.x;
        r[1] = R ? fmaxf(v.y, 0.f) : v.y;
    } else {
        static_assert(F % 4 == 0, "F must be 2 or multiple of 4");
#pragma unroll
        for (int k = 0; k < F; k += 4) {
            float4 v = *reinterpret_cast<const float4*>(p + k);
            r[k + 0] = R ? fmaxf(v.x, 0.f) : v.x;
            r[k + 1] = R ? fmaxf(v.y, 0.f) : v.y;
            r[k + 2] = R ? fmaxf(v.z, 0.f) : v.z;
            r[k + 3] = R ? fmaxf(v.w, 0.f) : v.w;
        }
    }
}

// out[dst] += ((relu?(x1[src]) ++ relu?(x2[src])) @ W) * ea   (atomic)
template<int FI1, int FI2, int FO, bool R1, bool R2>
__global__ void __launch_bounds__(256)
edge_conv_k(const float* __restrict__ x1, const float* __restrict__ x2,
            const int* __restrict__ src, const int* __restrict__ dst,
            const float* __restrict__ ea, const float* __restrict__ W,
            float* __restrict__ out, int E)
{
    constexpr int FI = FI1 + FI2;
    __shared__ float sW[FI * FO];
    for (int i = threadIdx.x; i < FI * FO; i += 256) sW[i] = W[i];
    __syncthreads();

    int e = blockIdx.x * 256 + threadIdx.x;
    if (e >= E) return;
    int s = src[e], d = dst[e];
    float w = ea[e];

    float xin[FI];
    load_feats<FI1, R1>(x1 + (size_t)s * FI1, xin);
    if constexpr (FI2 > 0)
        load_feats<FI2, R2>(x2 + (size_t)s * FI2, xin + FI1);

    float* outp = out + (size_t)d * FO;
#pragma unroll
    for (int fo = 0; fo < FO; ++fo) {
        float acc = 0.f;
#pragma unroll
        for (int k = 0; k < FI; ++k) acc = fmaf(xin[k], sW[k * FO + fo], acc);
        atomicAdd(outp + fo, acc * w);
    }
}

// out[dst] += ea * relu?(x[src])   (atomic)
template<int F, bool R>
__global__ void __launch_bounds__(256)
scatter_w_k(const float* __restrict__ x,
            const int* __restrict__ src, const int* __restrict__ dst,
            const float* __restrict__ ea, float* __restrict__ out, int E)
{
    int e = blockIdx.x * 256 + threadIdx.x;
    if (e >= E) return;
    int s = src[e], d = dst[e];
    float w = ea[e];
    const float* xp = x + (size_t)s * F;
    float* outp = out + (size_t)d * F;
#pragma unroll
    for (int k = 0; k < F; k += 4) {
        float4 v = *reinterpret_cast<const float4*>(xp + k);
        if (R) { v.x = fmaxf(v.x, 0.f); v.y = fmaxf(v.y, 0.f);
                 v.z = fmaxf(v.z, 0.f); v.w = fmaxf(v.w, 0.f); }
        atomicAdd(outp + k + 0, v.x * w);
        atomicAdd(outp + k + 1, v.y * w);
        atomicAdd(outp + k + 2, v.z * w);
        atomicAdd(outp + k + 3, v.w * w);
    }
}

// out[r][k] = b[k]  for all rows
template<int FO>
__global__ void __launch_bounds__(256)
init_bias_k(float* __restrict__ out, const float* __restrict__ b, int n)
{
    float bb[FO];
#pragma unroll
    for (int k = 0; k < FO; ++k) bb[k] = b[k];
    int r = blockIdx.x * 256 + threadIdx.x;
    if (r >= n) return;
    float* p = out + (size_t)r * FO;
#pragma unroll
    for (int k = 0; k < FO; k += 4)
        *reinterpret_cast<float4*>(p + k) = make_float4(bb[k], bb[k+1], bb[k+2], bb[k+3]);
}

// out[i] = relu(c9b[i,:]) . Wf + bf
__global__ void __launch_bounds__(256)
final_k(const float* __restrict__ c9b, const float* __restrict__ Wf,
        const float* __restrict__ bf, float* __restrict__ out, int n)
{
    __shared__ float sw[16];
    __shared__ float sb;
    if (threadIdx.x < 16) sw[threadIdx.x] = Wf[threadIdx.x];
    if (threadIdx.x == 0) sb = bf[0];
    __syncthreads();
    int i = blockIdx.x * 256 + threadIdx.x;
    if (i >= n) return;
    const float* p = c9b + (size_t)i * 16;
    float acc = sb;
#pragma unroll
    for (int k = 0; k < 16; k += 4) {
        float4 v = *reinterpret_cast<const float4*>(p + k);
        acc = fmaf(fmaxf(v.x, 0.f), sw[k + 0], acc);
        acc = fmaf(fmaxf(v.y, 0.f), sw[k + 1], acc);
        acc = fmaf(fmaxf(v.z, 0.f), sw[k + 2], acc);
        acc = fmaf(fmaxf(v.w, 0.f), sw[k + 3], acc);
    }
    out[i] = acc;
}

extern "C" void kernel_launch(void* const* d_in, const int* in_sizes, int n_in,
                              void* d_out, int out_size, void* d_ws, size_t ws_size,
                              hipStream_t stream)
{
    const float* xc = (const float*)d_in[0];
    const float* xf = (const float*)d_in[1];

    // edge sets: each name contributes d_in[i] = ei (2 x E ints, row0=src,
    // row1=dst) followed by d_in[i+1] = ea (E floats).
    auto SRC = [&](int i) { return (const int*)d_in[i]; };
    auto DST = [&](int i) { return (const int*)d_in[i] + in_sizes[i] / 2; };
    auto EA  = [&](int i) { return (const float*)d_in[i + 1]; };   // R1 FIX
    auto EN  = [&](int i) { return in_sizes[i] / 2; };

    const int i_cf = 2, i_fp = 4, i_pc = 6, i_pp0 = 8, i_pp1 = 10, i_pp2 = 12,
              i_pp3 = 14, i_pp4 = 16, i_po0 = 18, i_po1 = 20, i_po2 = 22,
              i_po3 = 24, i_up0 = 26, i_up1 = 28, i_up2 = 30, i_up3 = 32;

    const float* W_cf = (const float*)d_in[34]; const float* b_cf = (const float*)d_in[35];
    const float* W_fp = (const float*)d_in[36]; const float* b_fp = (const float*)d_in[37];
    const float* W2   = (const float*)d_in[38]; const float* b2   = (const float*)d_in[39];
    const float* W3   = (const float*)d_in[40]; const float* b3   = (const float*)d_in[41];
    const float* W4   = (const float*)d_in[42]; const float* b4   = (const float*)d_in[43];
    const float* W5a  = (const float*)d_in[44]; const float* b5a  = (const float*)d_in[45];
    const float* W5b  = (const float*)d_in[46]; const float* b5b  = (const float*)d_in[47];
    const float* W6   = (const float*)d_in[48]; const float* b6   = (const float*)d_in[49];
    const float* W7   = (const float*)d_in[50]; const float* b7   = (const float*)d_in[51];
    const float* W8   = (const float*)d_in[52]; const float* b8   = (const float*)d_in[53];
    const float* W9a  = (const float*)d_in[54]; const float* b9a  = (const float*)d_in[55];
    const float* W9b  = (const float*)d_in[56]; const float* b9b  = (const float*)d_in[57];
    const float* Wf   = (const float*)d_in[58]; const float* bfb  = (const float*)d_in[59];

    float* ws = (float*)d_ws;
    // scratch layout (floats). h-region reused for c9b; p1-region reused for g8.
    float* h    = ws + 0;           // NF*12 = 18,000,000 (>= c9b 16,000,000)
    float* c1   = ws + 18000000;    // N0*16 =  8,000,000
    float* p1   = ws + 26000000;    // N1*16 =  2,000,000 (reused for g8)
    float* c2   = ws + 28000000;    // N1*16 =  2,000,000
    float* p2   = ws + 30000000;    // N2*16 =    500,000
    float* c3   = ws + 30500000;    // N2*16 =    500,000
    float* p3   = ws + 31000000;    // N3*16 =    125,008
    float* c4   = ws + 31125008;    // N3*32 =    250,016
    float* p4   = ws + 31375024;    // N4*32 =     62,528
    float* c5a  = ws + 31437552;    // N4*32
    float* c5b  = ws + 31500080;    // N4*32
    float* u3   = ws + 31562608;    // N3*32 =    250,016
    float* g6   = ws + 31812624;    // N3*32
    float* c6   = ws + 32062640;    // N2*32 =  1,000,000
    float* g7   = ws + 33062640;    // N2*32
    float* c7   = ws + 34062640;    // N1*32 =  4,000,000
    float* g8   = p1;               // N1*16 =  2,000,000
    float* c8   = ws + 38062640;    // N0*16 =  8,000,000
    float* c9a  = ws + 46062640;    // N0*16 =  8,000,000
    float* c9b  = h;                // NC*16 = 16,000,000
    float* out  = (float*)d_out;

    const int B = 256;
    auto G = [&](int n) { return dim3((unsigned)((n + B - 1) / B)); };

    // zero-init all scatter_w targets (p1,p2,p3,p4,u3,c6,c7,c8 live in
    // [26,000,000 , 46,062,640); the conv buffers inside are bias-inited
    // before use, so one bulk memset is safe).
    hipMemsetAsync(ws + 26000000, 0, (size_t)(46062640 - 26000000) * 4, stream);

    // 1) h = conv(xc; cf)  [NF,12] pre-act
    init_bias_k<12><<<G(NFc), B, 0, stream>>>(h, b_cf, NFc);
    edge_conv_k<2, 0, 12, false, false><<<G(EN(i_cf)), B, 0, stream>>>(
        xc, nullptr, SRC(i_cf), DST(i_cf), EA(i_cf), W_cf, h, EN(i_cf));

    // 2) c1 = conv(concat(relu(h), xf); fp)  [N0,16] pre-act
    init_bias_k<16><<<G(N0c), B, 0, stream>>>(c1, b_fp, N0c);
    edge_conv_k<12, 4, 16, true, false><<<G(EN(i_fp)), B, 0, stream>>>(
        h, xf, SRC(i_fp), DST(i_fp), EA(i_fp), W_fp, c1, EN(i_fp));

    // 3) p1 = scatter_w(relu(c1); pool0)  [N1,16]
    scatter_w_k<16, true><<<G(EN(i_po0)), B, 0, stream>>>(
        c1, SRC(i_po0), DST(i_po0), EA(i_po0), p1, EN(i_po0));

    // 4) c2 = conv(p1; pp1, W2)  [N1,16] pre-act
    init_bias_k<16><<<G(N1c), B, 0, stream>>>(c2, b2, N1c);
    edge_conv_k<16, 0, 16, false, false><<<G(EN(i_pp1)), B, 0, stream>>>(
        p1, nullptr, SRC(i_pp1), DST(i_pp1), EA(i_pp1), W2, c2, EN(i_pp1));

    // 5) p2 = scatter_w(relu(c2); pool1)  [N2,16]
    scatter_w_k<16, true><<<G(EN(i_po1)), B, 0, stream>>>(
        c2, SRC(i_po1), DST(i_po1), EA(i_po1), p2, EN(i_po1));

    // 6) c3 = conv(p2; pp2, W3)  [N2,16] pre-act
    init_bias_k<16><<<G(N2c), B, 0, stream>>>(c3, b3, N2c);
    edge_conv_k<16, 0, 16, false, false><<<G(EN(i_pp2)), B, 0, stream>>>(
        p2, nullptr, SRC(i_pp2), DST(i_pp2), EA(i_pp2), W3, c3, EN(i_pp2));

    // 7) p3 = scatter_w(relu(c3); pool2)  [N3,16]
    scatter_w_k<16, true><<<G(EN(i_po2)), B, 0, stream>>>(
        c3, SRC(i_po2), DST(i_po2), EA(i_po2), p3, EN(i_po2));

    // 8) c4 = conv(p3; pp3, W4)  [N3,32] pre-act
    init_bias_k<32><<<G(N3c), B, 0, stream>>>(c4, b4, N3c);
    edge_conv_k<16, 0, 32, false, false><<<G(EN(i_pp3)), B, 0, stream>>>(
        p3, nullptr, SRC(i_pp3), DST(i_pp3), EA(i_pp3), W4, c4, EN(i_pp3));

    // 9) p4 = scatter_w(relu(c4); pool3)  [N4,32]
    scatter_w_k<32, true><<<G(EN(i_po3)), B, 0, stream>>>(
        c4, SRC(i_po3), DST(i_po3), EA(i_po3), p4, EN(i_po3));

    // 10) c5a = conv(p4; pp4, W5a)  [N4,32]
    init_bias_k<32><<<G(N4c), B, 0, stream>>>(c5a, b5a, N4c);
    edge_conv_k<32, 0, 32, false, false><<<G(EN(i_pp4)), B, 0, stream>>>(
        p4, nullptr, SRC(i_pp4), DST(i_pp4), EA(i_pp4), W5a, c5a, EN(i_pp4));

    // 11) c5b = conv(relu(c5a); pp4, W5b)  [N4,32]
    init_bias_k<32><<<G(N4c), B, 0, stream>>>(c5b, b5b, N4c);
    edge_conv_k<32, 0, 32, true, false><<<G(EN(i_pp4)), B, 0, stream>>>(
        c5a, nullptr, SRC(i_pp4), DST(i_pp4), EA(i_pp4), W5b, c5b, EN(i_pp4));

    // 12) u3 = scatter_w(relu(c5b); unpool3)  [N3,32]
    scatter_w_k<32, true><<<G(EN(i_up3)), B, 0, stream>>>(
        c5b, SRC(i_up3), DST(i_up3), EA(i_up3), u3, EN(i_up3));

    // 13) g6 = conv(concat(u3, relu(c4)); pp3, W6)  [N3,32]
    init_bias_k<32><<<G(N3c), B, 0, stream>>>(g6, b6, N3c);
    edge_conv_k<32, 32, 32, false, true><<<G(EN(i_pp3)), B, 0, stream>>>(
        u3, c4, SRC(i_pp3), DST(i_pp3), EA(i_pp3), W6, g6, EN(i_pp3));

    // 14) c6 = scatter_w(relu(g6); unpool2)  [N2,32]
    scatter_w_k<32, true><<<G(EN(i_up2)), B, 0, stream>>>(
        g6, SRC(i_up2), DST(i_up2), EA(i_up2), c6, EN(i_up2));

    // 15) g7 = conv(concat(c6, relu(c3)); pp2, W7)  [N2,32]
    init_bias_k<32><<<G(N2c), B, 0, stream>>>(g7, b7, N2c);
    edge_conv_k<32, 16, 32, false, true><<<G(EN(i_pp2)), B, 0, stream>>>(
        c6, c3, SRC(i_pp2), DST(i_pp2), EA(i_pp2), W7, g7, EN(i_pp2));

    // 16) c7 = scatter_w(relu(g7); unpool1)  [N1,32]
    scatter_w_k<32, true><<<G(EN(i_up1)), B, 0, stream>>>(
        g7, SRC(i_up1), DST(i_up1), EA(i_up1), c7, EN(i_up1));

    // 17) g8 = conv(concat(c7, relu(c2)); pp1, W8)  [N1,16]
    init_bias_k<16><<<G(N1c), B, 0, stream>>>(g8, b8, N1c);
    edge_conv_k<32, 16, 16, false, true><<<G(EN(i_pp1)), B, 0, stream>>>(
        c7, c2, SRC(i_pp1), DST(i_pp1), EA(i_pp1), W8, g8, EN(i_pp1));

    // 18) c8 = scatter_w(relu(g8); unpool0)  [N0,16]
    scatter_w_k<16, true><<<G(EN(i_up0)), B, 0, stream>>>(
        g8, SRC(i_up0), DST(i_up0), EA(i_up0), c8, EN(i_up0));

    // 19) c9a = conv(concat(c8, relu(c1)); pp0, W9a)  [N0,16]
    init_bias_k<16><<<G(N0c), B, 0, stream>>>(c9a, b9a, N0c);
    edge_conv_k<16, 16, 16, false, true><<<G(EN(i_pp0)), B, 0, stream>>>(
        c8, c1, SRC(i_pp0), DST(i_pp0), EA(i_pp0), W9a, c9a, EN(i_pp0));

    // 20) c9b = conv(relu(c9a); pc, W9b)  [NC,16]
    init_bias_k<16><<<G(NCc), B, 0, stream>>>(c9b, b9b, NCc);
    edge_conv_k<16, 0, 16, true, false><<<G(EN(i_pc)), B, 0, stream>>>(
        c9a, nullptr, SRC(i_pc), DST(i_pc), EA(i_pc), W9b, c9b, EN(i_pc));

    // 21) out = relu(c9b) @ Wf + bf
    final_k<<<G(NCc), B, 0, stream>>>(c9b, Wf, bfb, out, NCc);
}

// Round 4
// 2535.005 us; speedup vs baseline: 6.0873x; 6.0873x over previous
//
#include <hip/hip_runtime.h>
#include <cstdint>
#include <cstddef>

// ---------------------------------------------------------------------------
// GraphUNetSmall, round 4: atomic-free CSR+gather (R3 logic) with a
// lifetime-overlapped workspace layout.
//
// R3 post-mortem: bump allocator used 362 MB of d_ws; R2 proved only
// >=216 MB exists -> OOB writes -> HSA abort. This version packs everything
// into 4 zones totalling ~204.6 MB (< 216 MB proven safe):
//   ZoneA: cf+fp CSRs (steps 1-2), REBUILT in place as pc+pp0 CSRs (19/21).
//   ZoneB: 12 mid CSRs (steps 3-18), then t9 (step 19). Stage-I temps early.
//   ZoneC: c1 (steps 2-19), then tpc (20-21).
//   ZoneD: h (1-2), then stage-II build temps, then mid features;
//          c8/c9a overlay ZoneD[0,8M) after those mids are dead.
// Single-stream serialization makes every overlay safe (audited per step).
// ---------------------------------------------------------------------------

#define DEV __device__ __forceinline__

static constexpr int NCc = 1000000;
static constexpr int NFc = 1500000;
static constexpr int N0c = 500000;
static constexpr int N1c = 125000;
static constexpr int N2c = 31250;
static constexpr int N3c = 7813;
static constexpr int N4c = 1954;
static constexpr int SCHUNK = 2048;   // elems per scan block (256 thr * 8)

// ---------------- CSR build ----------------
__global__ void __launch_bounds__(256)
hist_rank_k(const int* __restrict__ dst, int* __restrict__ deg,
            int* __restrict__ rank, int E)
{
    int e = blockIdx.x * 256 + threadIdx.x;
    if (e < E) rank[e] = atomicAdd(&deg[dst[e]], 1);
}

__global__ void __launch_bounds__(256)
scan1_k(const int* __restrict__ deg, int* __restrict__ starts,
        int* __restrict__ part, int n)
{
    __shared__ int sd[256];
    int t = threadIdx.x;
    int base = blockIdx.x * SCHUNK + t * 8;
    int v[8]; int sum = 0;
#pragma unroll
    for (int k = 0; k < 8; ++k) { int i = base + k; v[k] = (i < n) ? deg[i] : 0; sum += v[k]; }
    sd[t] = sum; __syncthreads();
    for (int off = 1; off < 256; off <<= 1) {
        int y = (t >= off) ? sd[t - off] : 0;
        __syncthreads();
        sd[t] += y;
        __syncthreads();
    }
    int run = sd[t] - sum;                 // exclusive offset of this thread
#pragma unroll
    for (int k = 0; k < 8; ++k) { int i = base + k; if (i < n) starts[i] = run; run += v[k]; }
    if (t == 255) part[blockIdx.x] = sd[255];
}

__global__ void __launch_bounds__(1024)
scan2_k(int* __restrict__ part, int nb)   // exclusive scan of block sums, nb<=1024
{
    __shared__ int sd[1024];
    int t = threadIdx.x;
    int v = (t < nb) ? part[t] : 0;
    sd[t] = v; __syncthreads();
    for (int off = 1; off < 1024; off <<= 1) {
        int y = (t >= off) ? sd[t - off] : 0;
        __syncthreads();
        sd[t] += y;
        __syncthreads();
    }
    if (t < nb) part[t] = sd[t] - v;
}

__global__ void __launch_bounds__(256)
scan3_k(int* __restrict__ starts, const int* __restrict__ part, int n, int E)
{
    int i = blockIdx.x * 256 + threadIdx.x;
    if (i < n) starts[i] += part[i / SCHUNK];
    if (i == 0) starts[n] = E;
}

__global__ void __launch_bounds__(256)
reorder_k(const int* __restrict__ src, const int* __restrict__ dst,
          const float* __restrict__ ea, const int* __restrict__ rank,
          const int* __restrict__ starts, int2* __restrict__ ecsr, int E)
{
    int e = blockIdx.x * 256 + threadIdx.x;
    if (e >= E) return;
    int p = starts[dst[e]] + rank[e];
    ecsr[p] = make_int2(src[e], __float_as_int(ea[e]));
}

// ---------------- compute ----------------
template<int F>
DEV void row_fma(const float* __restrict__ p, float w, float* acc)
{
    if constexpr (F == 2) {
        float2 v = *reinterpret_cast<const float2*>(p);
        acc[0] = fmaf(w, v.x, acc[0]); acc[1] = fmaf(w, v.y, acc[1]);
    } else {
        static_assert(F % 4 == 0, "");
#pragma unroll
        for (int k = 0; k < F; k += 4) {
            float4 v = *reinterpret_cast<const float4*>(p + k);
            acc[k+0] = fmaf(w, v.x, acc[k+0]); acc[k+1] = fmaf(w, v.y, acc[k+1]);
            acc[k+2] = fmaf(w, v.z, acc[k+2]); acc[k+3] = fmaf(w, v.w, acc[k+3]);
        }
    }
}

// out[d] = sum_{edges into d} w * x[s]   (+b, relu if EPI)
template<int F, bool EPI>
__global__ void __launch_bounds__(256)
gather_sw_k(const float* __restrict__ x, const int2* __restrict__ ecsr,
            const int* __restrict__ starts, const float* __restrict__ b,
            float* __restrict__ out, int n)
{
    int d = blockIdx.x * 256 + threadIdx.x;
    if (d >= n) return;
    int i0 = starts[d], i1 = starts[d + 1];
    float acc[F];
#pragma unroll
    for (int k = 0; k < F; ++k) acc[k] = 0.f;
    for (int i = i0; i < i1; ++i) {
        int2 rec = ecsr[i];
        row_fma<F>(x + (size_t)rec.x * F, __int_as_float(rec.y), acc);
    }
    if constexpr (EPI) {
#pragma unroll
        for (int k = 0; k < F; ++k) acc[k] = fmaxf(acc[k] + b[k], 0.f);
    }
    float* op = out + (size_t)d * F;
#pragma unroll
    for (int k = 0; k < F; k += 4)
        *reinterpret_cast<float4*>(op + k) = make_float4(acc[k], acc[k+1], acc[k+2], acc[k+3]);
}

// out[d] = relu( (sum_e w*concat(x1[s],x2[s])) @ W + b )
template<int FI1, int FI2, int FO>
__global__ void __launch_bounds__(256)
gather_conv_k(const float* __restrict__ x1, const float* __restrict__ x2,
              const int2* __restrict__ ecsr, const int* __restrict__ starts,
              const float* __restrict__ W, const float* __restrict__ b,
              float* __restrict__ out, int n)
{
    constexpr int FI = FI1 + FI2;
    __shared__ float sW[FI * FO];
    for (int i = threadIdx.x; i < FI * FO; i += 256) sW[i] = W[i];
    __syncthreads();
    int d = blockIdx.x * 256 + threadIdx.x;
    if (d >= n) return;
    int i0 = starts[d], i1 = starts[d + 1];
    float acc[FI];
#pragma unroll
    for (int k = 0; k < FI; ++k) acc[k] = 0.f;
    for (int i = i0; i < i1; ++i) {
        int2 rec = ecsr[i];
        float w = __int_as_float(rec.y);
        row_fma<FI1>(x1 + (size_t)rec.x * FI1, w, acc);
        if constexpr (FI2 > 0)
            row_fma<FI2>(x2 + (size_t)rec.x * FI2, w, acc + FI1);
    }
    float* op = out + (size_t)d * FO;
#pragma unroll
    for (int fo = 0; fo < FO; fo += 4) {
        float4 y;
        float* yp = &y.x;
#pragma unroll
        for (int j = 0; j < 4; ++j) {
            float s = b[fo + j];
#pragma unroll
            for (int k = 0; k < FI; ++k) s = fmaf(acc[k], sW[k * FO + fo + j], s);
            yp[j] = fmaxf(s, 0.f);
        }
        *reinterpret_cast<float4*>(op + fo) = y;
    }
}

// out[i] = concat(x1[i], x2[i]) @ W      (no bias / relu; used pre-scatter)
template<int FI1, int FI2, int FO>
__global__ void __launch_bounds__(256)
dense2_k(const float* __restrict__ x1, const float* __restrict__ x2,
         const float* __restrict__ W, float* __restrict__ out, int n)
{
    constexpr int FI = FI1 + FI2;
    __shared__ float sW[FI * FO];
    for (int i = threadIdx.x; i < FI * FO; i += 256) sW[i] = W[i];
    __syncthreads();
    int d = blockIdx.x * 256 + threadIdx.x;
    if (d >= n) return;
    float xin[FI];
    {
        const float* p = x1 + (size_t)d * FI1;
#pragma unroll
        for (int k = 0; k < FI1; k += 4) {
            float4 v = *reinterpret_cast<const float4*>(p + k);
            xin[k] = v.x; xin[k+1] = v.y; xin[k+2] = v.z; xin[k+3] = v.w;
        }
    }
    if constexpr (FI2 > 0) {
        const float* p = x2 + (size_t)d * FI2;
#pragma unroll
        for (int k = 0; k < FI2; k += 4) {
            float4 v = *reinterpret_cast<const float4*>(p + k);
            xin[FI1+k] = v.x; xin[FI1+k+1] = v.y; xin[FI1+k+2] = v.z; xin[FI1+k+3] = v.w;
        }
    }
    float* op = out + (size_t)d * FO;
#pragma unroll
    for (int fo = 0; fo < FO; fo += 4) {
        float4 y; float* yp = &y.x;
#pragma unroll
        for (int j = 0; j < 4; ++j) {
            float s = 0.f;
#pragma unroll
            for (int k = 0; k < FI; ++k) s = fmaf(xin[k], sW[k * FO + fo + j], s);
            yp[j] = s;
        }
        *reinterpret_cast<float4*>(op + fo) = y;
    }
}

// out[d] = relu(gather + b9b) . Wf + bf   (final readout fused into pc gather)
__global__ void __launch_bounds__(256)
gather_final_k(const float* __restrict__ x, const int2* __restrict__ ecsr,
               const int* __restrict__ starts, const float* __restrict__ b9b,
               const float* __restrict__ Wf, const float* __restrict__ bf,
               float* __restrict__ out, int n)
{
    int d = blockIdx.x * 256 + threadIdx.x;
    if (d >= n) return;
    int i0 = starts[d], i1 = starts[d + 1];
    float acc[16];
#pragma unroll
    for (int k = 0; k < 16; ++k) acc[k] = 0.f;
    for (int i = i0; i < i1; ++i) {
        int2 rec = ecsr[i];
        row_fma<16>(x + (size_t)rec.x * 16, __int_as_float(rec.y), acc);
    }
    float y = bf[0];
#pragma unroll
    for (int k = 0; k < 16; ++k) y = fmaf(fmaxf(acc[k] + b9b[k], 0.f), Wf[k], y);
    out[d] = y;
}

// ---------------- host ----------------
extern "C" void kernel_launch(void* const* d_in, const int* in_sizes, int n_in,
                              void* d_out, int out_size, void* d_ws, size_t ws_size,
                              hipStream_t stream)
{
    const float* xc = (const float*)d_in[0];
    const float* xf = (const float*)d_in[1];

    auto SRC = [&](int i) { return (const int*)d_in[i]; };
    auto DST = [&](int i) { return (const int*)d_in[i] + in_sizes[i] / 2; };
    auto EA  = [&](int i) { return (const float*)d_in[i + 1]; };
    auto EN  = [&](int i) { return in_sizes[i] / 2; };

    // set order: cf fp pc pp0 pp1 pp2 pp3 pp4 po0 po1 po2 po3 up0 up1 up2 up3
    enum { s_cf, s_fp, s_pc, s_pp0, s_pp1, s_pp2, s_pp3, s_pp4,
           s_po0, s_po1, s_po2, s_po3, s_up0, s_up1, s_up2, s_up3 };
    const int setIn[16] = {2,4,6,8,10,12,14,16,18,20,22,24,26,28,30,32};
    const int setNd[16] = {NFc,N0c,NCc,N0c,N1c,N2c,N3c,N4c,
                           N1c,N2c,N3c,N4c, N0c,N1c,N2c,N3c};

    const float* W_cf=(const float*)d_in[34]; const float* b_cf=(const float*)d_in[35];
    const float* W_fp=(const float*)d_in[36]; const float* b_fp=(const float*)d_in[37];
    const float* W2  =(const float*)d_in[38]; const float* b2  =(const float*)d_in[39];
    const float* W3  =(const float*)d_in[40]; const float* b3  =(const float*)d_in[41];
    const float* W4  =(const float*)d_in[42]; const float* b4  =(const float*)d_in[43];
    const float* W5a =(const float*)d_in[44]; const float* b5a =(const float*)d_in[45];
    const float* W5b =(const float*)d_in[46]; const float* b5b =(const float*)d_in[47];
    const float* W6  =(const float*)d_in[48]; const float* b6  =(const float*)d_in[49];
    const float* W7  =(const float*)d_in[50]; const float* b7  =(const float*)d_in[51];
    const float* W8  =(const float*)d_in[52]; const float* b8  =(const float*)d_in[53];
    const float* W9a =(const float*)d_in[54]; const float* b9a =(const float*)d_in[55];
    const float* W9b =(const float*)d_in[56]; const float* b9b =(const float*)d_in[57];
    const float* Wf  =(const float*)d_in[58]; const float* bfb =(const float*)d_in[59];

    float* ws = (float*)d_ws;
    auto pad4 = [](size_t x) { return (x + 3) & ~(size_t)3; };
    // CSR footprint (float units) for set t: starts (Nd+1) + ecsr (2*E)
    auto csrU = [&](int t) {
        return pad4((size_t)setNd[t] + 1) + pad4((size_t)2 * EN(setIn[t]));
    };

    // ---- zone sizing (units of 4 B) ----
    size_t sumM = 0;
    for (int t = s_pp1; t <= s_up3; ++t) sumM += csrU(t);    // pp1..pp4, po*, up*
    size_t zA = csrU(s_cf) + csrU(s_fp);
    { size_t alt = csrU(s_pc) + csrU(s_pp0); if (alt > zA) zA = alt; }
    size_t zB = sumM; { size_t alt = (size_t)N0c * 16; if (alt > zB) zB = alt; }
    size_t zC = (size_t)N0c * 16;                            // c1 / tpc
    size_t zD = (size_t)NFc * 12;                            // >= mids (17.31M)
    size_t zA_o = 0, zB_o = zA, zC_o = zA + zB, zD_o = zA + zB + zC;
    size_t part_o = zD_o + zD;                               // +1024 ints
    // total ~51.14M units ~204.6 MB  (< 216 MB proven available in R2)

    // per-set CSR pointers (ZoneA double-booked in time: cf/fp then pc/pp0)
    int*  st[16]; int2* ec[16];
    auto place = [&](int t, size_t o) {
        st[t] = (int*)(ws + o);
        ec[t] = (int2*)(ws + o + pad4((size_t)setNd[t] + 1));
    };
    place(s_cf, zA_o);
    place(s_fp, zA_o + csrU(s_cf));
    place(s_pc, zA_o);                       // rebuilt after step 2
    place(s_pp0, zA_o + csrU(s_pc));
    { size_t o = zB_o; for (int t = s_pp1; t <= s_up3; ++t) { place(t, o); o += csrU(t); } }

    int* part = (int*)(ws + part_o);

    const int B = 256;
    auto G = [&](int n) { return dim3((unsigned)((n + B - 1) / B)); };

    auto build = [&](int t, int* rank, int* deg) {
        int ii = setIn[t], E = EN(ii), Nd = setNd[t];
        hipMemsetAsync(deg, 0, (size_t)Nd * 4, stream);
        hist_rank_k<<<G(E), B, 0, stream>>>(DST(ii), deg, rank, E);
        int nb = (Nd + SCHUNK - 1) / SCHUNK;
        scan1_k<<<dim3((unsigned)nb), B, 0, stream>>>(deg, st[t], part, Nd);
        scan2_k<<<1, 1024, 0, stream>>>(part, nb);
        scan3_k<<<G(Nd), B, 0, stream>>>(st[t], part, Nd, E);
        reorder_k<<<G(E), B, 0, stream>>>(SRC(ii), DST(ii), EA(ii), rank, st[t], ec[t], E);
    };

    // ---- feature buffers ----
    float* h   = ws + zD_o;                  // [NF,12], steps 1-2
    float* c1  = ws + zC_o;                  // [N0,16], steps 2-19
    float* tpc = c1;                         // steps 20-21 (c1 dead)
    // mids bump inside ZoneD (h dead once these are written, step >=3)
    size_t mb = zD_o;
    auto mal = [&](size_t n) { size_t o = mb; mb += pad4(n); return ws + o; };
    float* p1  = mal((size_t)N1c*16);
    float* c2  = mal((size_t)N1c*16);
    float* p2  = mal((size_t)N2c*16);
    float* c3  = mal((size_t)N2c*16);
    float* p3  = mal((size_t)N3c*16);
    float* c4  = mal((size_t)N3c*32);
    float* p4  = mal((size_t)N4c*32);
    float* c5a = mal((size_t)N4c*32);
    float* c5b = mal((size_t)N4c*32);
    float* u3  = mal((size_t)N3c*32);
    float* t6  = mal((size_t)N3c*32);
    float* g6  = mal((size_t)N3c*32);
    float* c6  = mal((size_t)N2c*32);
    float* t7  = mal((size_t)N2c*32);
    float* g7  = mal((size_t)N2c*32);
    float* c7  = mal((size_t)N1c*32);
    float* t8  = mal((size_t)N1c*16);
    float* g8  = mal((size_t)N1c*16);        // mb ~ zD_o+17.31M <= zD_o+18M
    float* c8  = ws + zD_o;                  // overlay [0,8M): all dead by 18
    float* c9a = ws + zD_o;                  // overlay again after c8 dies (19)
    float* t9  = ws + zB_o;                  // ZoneB: M CSRs dead after 18
    float* out = (float*)d_out;

    // build temps: stage I in ZoneB (free), stage II in ZoneD (h dead)
    int* rankB = (int*)(ws + zB_o);
    int* degB  = rankB + 3000000 + 16;       // E_cf/E_fp <= 3,000,000
    int* rankD = (int*)(ws + zD_o);
    int* degD  = rankD + 4000000 + 16;       // E_pc <= 4,000,000

    // ---- Stage I: cf/fp CSRs + steps 1-2 ----
    build(s_cf, rankB, degB);
    build(s_fp, rankB, degB);
    // 1) h = relu(gather(cf, xc) @ W_cf + b_cf)                [NF,12]
    gather_conv_k<2,0,12><<<G(NFc), B, 0, stream>>>(xc, nullptr, ec[s_cf], st[s_cf], W_cf, b_cf, h, NFc);
    // 2) c1 = relu(gather(fp, h||xf) @ W_fp + b_fp)            [N0,16]
    gather_conv_k<12,4,16><<<G(N0c), B, 0, stream>>>(h, xf, ec[s_fp], st[s_fp], W_fp, b_fp, c1, N0c);

    // ---- Stage II: remaining CSRs (ZoneA rebuilt, ZoneB filled) ----
    build(s_pc, rankD, degD);
    build(s_pp0, rankD, degD);
    for (int t = s_pp1; t <= s_up3; ++t) build(t, rankD, degD);

    // ---- Stage III: pipeline (zero atomics) ----
    // 3) p1 = gather(pool0, c1)
    gather_sw_k<16,false><<<G(N1c), B, 0, stream>>>(c1, ec[s_po0], st[s_po0], nullptr, p1, N1c);
    // 4) c2 = relu(gather(pp1, p1) @ W2 + b2)
    gather_conv_k<16,0,16><<<G(N1c), B, 0, stream>>>(p1, nullptr, ec[s_pp1], st[s_pp1], W2, b2, c2, N1c);
    // 5) p2
    gather_sw_k<16,false><<<G(N2c), B, 0, stream>>>(c2, ec[s_po1], st[s_po1], nullptr, p2, N2c);
    // 6) c3
    gather_conv_k<16,0,16><<<G(N2c), B, 0, stream>>>(p2, nullptr, ec[s_pp2], st[s_pp2], W3, b3, c3, N2c);
    // 7) p3
    gather_sw_k<16,false><<<G(N3c), B, 0, stream>>>(c3, ec[s_po2], st[s_po2], nullptr, p3, N3c);
    // 8) c4 = relu(gather(pp3, p3) @ W4 + b4)                  [N3,32]
    gather_conv_k<16,0,32><<<G(N3c), B, 0, stream>>>(p3, nullptr, ec[s_pp3], st[s_pp3], W4, b4, c4, N3c);
    // 9) p4
    gather_sw_k<32,false><<<G(N4c), B, 0, stream>>>(c4, ec[s_po3], st[s_po3], nullptr, p4, N4c);
    // 10) c5a
    gather_conv_k<32,0,32><<<G(N4c), B, 0, stream>>>(p4, nullptr, ec[s_pp4], st[s_pp4], W5a, b5a, c5a, N4c);
    // 11) c5b
    gather_conv_k<32,0,32><<<G(N4c), B, 0, stream>>>(c5a, nullptr, ec[s_pp4], st[s_pp4], W5b, b5b, c5b, N4c);
    // 12) u3
    gather_sw_k<32,false><<<G(N3c), B, 0, stream>>>(c5b, ec[s_up3], st[s_up3], nullptr, u3, N3c);
    // 13) g6: FI=64>FO=32 -> pre-transform then gather+bias+relu
    dense2_k<32,32,32><<<G(N3c), B, 0, stream>>>(u3, c4, W6, t6, N3c);
    gather_sw_k<32,true><<<G(N3c), B, 0, stream>>>(t6, ec[s_pp3], st[s_pp3], b6, g6, N3c);
    // 14) c6
    gather_sw_k<32,false><<<G(N2c), B, 0, stream>>>(g6, ec[s_up2], st[s_up2], nullptr, c6, N2c);
    // 15) g7 (48->32 pre)
    dense2_k<32,16,32><<<G(N2c), B, 0, stream>>>(c6, c3, W7, t7, N2c);
    gather_sw_k<32,true><<<G(N2c), B, 0, stream>>>(t7, ec[s_pp2], st[s_pp2], b7, g7, N2c);
    // 16) c7
    gather_sw_k<32,false><<<G(N1c), B, 0, stream>>>(g7, ec[s_up1], st[s_up1], nullptr, c7, N1c);
    // 17) g8 (48->16 pre)
    dense2_k<32,16,16><<<G(N1c), B, 0, stream>>>(c7, c2, W8, t8, N1c);
    gather_sw_k<16,true><<<G(N1c), B, 0, stream>>>(t8, ec[s_pp1], st[s_pp1], b8, g8, N1c);
    // 18) c8 = gather(unpool0, g8)   [N0,16] -> ZoneD[0,8M) (mids dead)
    gather_sw_k<16,false><<<G(N0c), B, 0, stream>>>(g8, ec[s_up0], st[s_up0], nullptr, c8, N0c);
    // 19) c9a (32->16 pre): t9 in ZoneB (M CSRs dead), c9a overlays c8
    dense2_k<16,16,16><<<G(N0c), B, 0, stream>>>(c8, c1, W9a, t9, N0c);
    gather_sw_k<16,true><<<G(N0c), B, 0, stream>>>(t9, ec[s_pp0], st[s_pp0], b9a, c9a, N0c);
    // 20) pc conv pre-transform (N0 < NC so pre is cheaper); tpc overlays c1
    dense2_k<16,0,16><<<G(N0c), B, 0, stream>>>(c9a, nullptr, W9b, tpc, N0c);
    // 21) fused pc gather + bias + relu + Wf dot
    gather_final_k<<<G(NCc), B, 0, stream>>>(tpc, ec[s_pc], st[s_pc], b9b, Wf, bfb, out, NCc);
}

// Round 5
// 2431.142 us; speedup vs baseline: 6.3474x; 1.0427x over previous
//
#include <hip/hip_runtime.h>
#include <cstdint>
#include <cstddef>

// ---------------------------------------------------------------------------
// GraphUNetSmall, round 5: CSR+gather (R4) with latency-hidden CSR build.
//
// R4 post-mortem: hist_rank was LATENCY-bound at 1 outstanding
// atomic-with-return per wave (22.5 G/s == 8192 waves / 900cy). Fixes:
//   - hist8_k: 8 edges/thread -> 8 atomics in flight per lane.
//   - reorder4_k: 4 edges/thread for the starts[dst]+rank dependent loads.
//   - per-stage FUSED scan: deg arrays concatenated, one 3-level scan,
//     starts hold GLOBAL record indices into one shared pool per stage.
// Zones (204.6 MB total, R4-proven budget):
//   ZoneAB: stage-I (cf+fp starts+pool, steps 1-2) REBUILT as stage-II
//           (14 sets, steps 3-21). ZoneC: c1/tpc. ZoneD: build temps ->
//           h -> mids -> c8/t9/c9a overlays.
// ---------------------------------------------------------------------------

#define DEV __device__ __forceinline__

static constexpr int NCc = 1000000;
static constexpr int NFc = 1500000;
static constexpr int N0c = 500000;
static constexpr int N1c = 125000;
static constexpr int N2c = 31250;
static constexpr int N3c = 7813;
static constexpr int N4c = 1954;
static constexpr int SCHUNK = 8192;   // elems per scan block (256 thr * 32)

// ---------------- CSR build ----------------
// 8 edges/thread: independent atomics pipeline (latency hiding).
__global__ void __launch_bounds__(256)
hist8_k(const int* __restrict__ dst, int* __restrict__ deg,
        int* __restrict__ rank, int E)
{
    int base = blockIdx.x * 2048 + threadIdx.x;
    int d[8];
#pragma unroll
    for (int k = 0; k < 8; ++k) {
        int e = base + k * 256;
        d[k] = (e < E) ? dst[e] : -1;
    }
#pragma unroll
    for (int k = 0; k < 8; ++k) {
        int e = base + k * 256;
        if (e < E) rank[e] = atomicAdd(&deg[d[k]], 1);
    }
}

__global__ void __launch_bounds__(256)
scan1_k(const int* __restrict__ deg, int* __restrict__ starts,
        int* __restrict__ part, int n)
{
    __shared__ int sd[256];
    int t = threadIdx.x;
    int base = blockIdx.x * SCHUNK + t * 32;
    int v[32]; int sum = 0;
#pragma unroll
    for (int k = 0; k < 32; ++k) { int i = base + k; v[k] = (i < n) ? deg[i] : 0; sum += v[k]; }
    sd[t] = sum; __syncthreads();
    for (int off = 1; off < 256; off <<= 1) {
        int y = (t >= off) ? sd[t - off] : 0;
        __syncthreads();
        sd[t] += y;
        __syncthreads();
    }
    int run = sd[t] - sum;                 // exclusive offset of this thread
#pragma unroll
    for (int k = 0; k < 32; ++k) { int i = base + k; if (i < n) starts[i] = run; run += v[k]; }
    if (t == 255) part[blockIdx.x] = sd[255];
}

__global__ void __launch_bounds__(1024)
scan2_k(int* __restrict__ part, int nb)   // exclusive scan of block sums, nb<=1024
{
    __shared__ int sd[1024];
    int t = threadIdx.x;
    int v = (t < nb) ? part[t] : 0;
    sd[t] = v; __syncthreads();
    for (int off = 1; off < 1024; off <<= 1) {
        int y = (t >= off) ? sd[t - off] : 0;
        __syncthreads();
        sd[t] += y;
        __syncthreads();
    }
    if (t < nb) part[t] = sd[t] - v;
}

__global__ void __launch_bounds__(256)
scan3_k(int* __restrict__ starts, const int* __restrict__ part, int n, int Etot)
{
    int i = blockIdx.x * 256 + threadIdx.x;
    if (i < n) starts[i] += part[i / SCHUNK];
    if (i == 0) starts[n] = Etot;          // global sentinel
}

// 4 edges/thread; starts here is (starts_base + doff[set]); pool positions
// are GLOBAL record indices (fused scan), pool shared per stage.
__global__ void __launch_bounds__(256)
reorder4_k(const int* __restrict__ src, const int* __restrict__ dst,
           const float* __restrict__ ea, const int* __restrict__ rank,
           const int* __restrict__ starts, int2* __restrict__ pool, int E)
{
    int base = blockIdx.x * 1024 + threadIdx.x;
    int d4[4], r4[4], s4[4]; float w4[4];
#pragma unroll
    for (int k = 0; k < 4; ++k) {
        int e = base + k * 256;
        if (e < E) { d4[k] = dst[e]; s4[k] = src[e]; w4[k] = ea[e]; r4[k] = rank[e]; }
    }
#pragma unroll
    for (int k = 0; k < 4; ++k) {
        int e = base + k * 256;
        if (e < E) {
            int p = starts[d4[k]] + r4[k];
            pool[p] = make_int2(s4[k], __float_as_int(w4[k]));
        }
    }
}

// ---------------- compute (unchanged from R4) ----------------
template<int F>
DEV void row_fma(const float* __restrict__ p, float w, float* acc)
{
    if constexpr (F == 2) {
        float2 v = *reinterpret_cast<const float2*>(p);
        acc[0] = fmaf(w, v.x, acc[0]); acc[1] = fmaf(w, v.y, acc[1]);
    } else {
        static_assert(F % 4 == 0, "");
#pragma unroll
        for (int k = 0; k < F; k += 4) {
            float4 v = *reinterpret_cast<const float4*>(p + k);
            acc[k+0] = fmaf(w, v.x, acc[k+0]); acc[k+1] = fmaf(w, v.y, acc[k+1]);
            acc[k+2] = fmaf(w, v.z, acc[k+2]); acc[k+3] = fmaf(w, v.w, acc[k+3]);
        }
    }
}

template<int F, bool EPI>
__global__ void __launch_bounds__(256)
gather_sw_k(const float* __restrict__ x, const int2* __restrict__ ecsr,
            const int* __restrict__ starts, const float* __restrict__ b,
            float* __restrict__ out, int n)
{
    int d = blockIdx.x * 256 + threadIdx.x;
    if (d >= n) return;
    int i0 = starts[d], i1 = starts[d + 1];
    float acc[F];
#pragma unroll
    for (int k = 0; k < F; ++k) acc[k] = 0.f;
    for (int i = i0; i < i1; ++i) {
        int2 rec = ecsr[i];
        row_fma<F>(x + (size_t)rec.x * F, __int_as_float(rec.y), acc);
    }
    if constexpr (EPI) {
#pragma unroll
        for (int k = 0; k < F; ++k) acc[k] = fmaxf(acc[k] + b[k], 0.f);
    }
    float* op = out + (size_t)d * F;
#pragma unroll
    for (int k = 0; k < F; k += 4)
        *reinterpret_cast<float4*>(op + k) = make_float4(acc[k], acc[k+1], acc[k+2], acc[k+3]);
}

template<int FI1, int FI2, int FO>
__global__ void __launch_bounds__(256)
gather_conv_k(const float* __restrict__ x1, const float* __restrict__ x2,
              const int2* __restrict__ ecsr, const int* __restrict__ starts,
              const float* __restrict__ W, const float* __restrict__ b,
              float* __restrict__ out, int n)
{
    constexpr int FI = FI1 + FI2;
    __shared__ float sW[FI * FO];
    for (int i = threadIdx.x; i < FI * FO; i += 256) sW[i] = W[i];
    __syncthreads();
    int d = blockIdx.x * 256 + threadIdx.x;
    if (d >= n) return;
    int i0 = starts[d], i1 = starts[d + 1];
    float acc[FI];
#pragma unroll
    for (int k = 0; k < FI; ++k) acc[k] = 0.f;
    for (int i = i0; i < i1; ++i) {
        int2 rec = ecsr[i];
        float w = __int_as_float(rec.y);
        row_fma<FI1>(x1 + (size_t)rec.x * FI1, w, acc);
        if constexpr (FI2 > 0)
            row_fma<FI2>(x2 + (size_t)rec.x * FI2, w, acc + FI1);
    }
    float* op = out + (size_t)d * FO;
#pragma unroll
    for (int fo = 0; fo < FO; fo += 4) {
        float4 y; float* yp = &y.x;
#pragma unroll
        for (int j = 0; j < 4; ++j) {
            float s = b[fo + j];
#pragma unroll
            for (int k = 0; k < FI; ++k) s = fmaf(acc[k], sW[k * FO + fo + j], s);
            yp[j] = fmaxf(s, 0.f);
        }
        *reinterpret_cast<float4*>(op + fo) = y;
    }
}

template<int FI1, int FI2, int FO>
__global__ void __launch_bounds__(256)
dense2_k(const float* __restrict__ x1, const float* __restrict__ x2,
         const float* __restrict__ W, float* __restrict__ out, int n)
{
    constexpr int FI = FI1 + FI2;
    __shared__ float sW[FI * FO];
    for (int i = threadIdx.x; i < FI * FO; i += 256) sW[i] = W[i];
    __syncthreads();
    int d = blockIdx.x * 256 + threadIdx.x;
    if (d >= n) return;
    float xin[FI];
    {
        const float* p = x1 + (size_t)d * FI1;
#pragma unroll
        for (int k = 0; k < FI1; k += 4) {
            float4 v = *reinterpret_cast<const float4*>(p + k);
            xin[k] = v.x; xin[k+1] = v.y; xin[k+2] = v.z; xin[k+3] = v.w;
        }
    }
    if constexpr (FI2 > 0) {
        const float* p = x2 + (size_t)d * FI2;
#pragma unroll
        for (int k = 0; k < FI2; k += 4) {
            float4 v = *reinterpret_cast<const float4*>(p + k);
            xin[FI1+k] = v.x; xin[FI1+k+1] = v.y; xin[FI1+k+2] = v.z; xin[FI1+k+3] = v.w;
        }
    }
    float* op = out + (size_t)d * FO;
#pragma unroll
    for (int fo = 0; fo < FO; fo += 4) {
        float4 y; float* yp = &y.x;
#pragma unroll
        for (int j = 0; j < 4; ++j) {
            float s = 0.f;
#pragma unroll
            for (int k = 0; k < FI; ++k) s = fmaf(xin[k], sW[k * FO + fo + j], s);
            yp[j] = s;
        }
        *reinterpret_cast<float4*>(op + fo) = y;
    }
}

__global__ void __launch_bounds__(256)
gather_final_k(const float* __restrict__ x, const int2* __restrict__ ecsr,
               const int* __restrict__ starts, const float* __restrict__ b9b,
               const float* __restrict__ Wf, const float* __restrict__ bf,
               float* __restrict__ out, int n)
{
    int d = blockIdx.x * 256 + threadIdx.x;
    if (d >= n) return;
    int i0 = starts[d], i1 = starts[d + 1];
    float acc[16];
#pragma unroll
    for (int k = 0; k < 16; ++k) acc[k] = 0.f;
    for (int i = i0; i < i1; ++i) {
        int2 rec = ecsr[i];
        row_fma<16>(x + (size_t)rec.x * 16, __int_as_float(rec.y), acc);
    }
    float y = bf[0];
#pragma unroll
    for (int k = 0; k < 16; ++k) y = fmaf(fmaxf(acc[k] + b9b[k], 0.f), Wf[k], y);
    out[d] = y;
}

// ---------------- host ----------------
extern "C" void kernel_launch(void* const* d_in, const int* in_sizes, int n_in,
                              void* d_out, int out_size, void* d_ws, size_t ws_size,
                              hipStream_t stream)
{
    const float* xc = (const float*)d_in[0];
    const float* xf = (const float*)d_in[1];

    auto SRC = [&](int i) { return (const int*)d_in[i]; };
    auto DST = [&](int i) { return (const int*)d_in[i] + in_sizes[i] / 2; };
    auto EA  = [&](int i) { return (const float*)d_in[i + 1]; };
    auto EN  = [&](int i) { return in_sizes[i] / 2; };

    const float* W_cf=(const float*)d_in[34]; const float* b_cf=(const float*)d_in[35];
    const float* W_fp=(const float*)d_in[36]; const float* b_fp=(const float*)d_in[37];
    const float* W2  =(const float*)d_in[38]; const float* b2  =(const float*)d_in[39];
    const float* W3  =(const float*)d_in[40]; const float* b3  =(const float*)d_in[41];
    const float* W4  =(const float*)d_in[42]; const float* b4  =(const float*)d_in[43];
    const float* W5a =(const float*)d_in[44]; const float* b5a =(const float*)d_in[45];
    const float* W5b =(const float*)d_in[46]; const float* b5b =(const float*)d_in[47];
    const float* W6  =(const float*)d_in[48]; const float* b6  =(const float*)d_in[49];
    const float* W7  =(const float*)d_in[50]; const float* b7  =(const float*)d_in[51];
    const float* W8  =(const float*)d_in[52]; const float* b8  =(const float*)d_in[53];
    const float* W9a =(const float*)d_in[54]; const float* b9a =(const float*)d_in[55];
    const float* W9b =(const float*)d_in[56]; const float* b9b =(const float*)d_in[57];
    const float* Wf  =(const float*)d_in[58]; const float* bfb =(const float*)d_in[59];

    float* ws = (float*)d_ws;
    auto pad4 = [](size_t x) { return (x + 3) & ~(size_t)3; };

    // stage set lists (input index, n_dst). Stage II order puts pc, pp0 first
    // (their CSRs are read last, at steps 19/21).
    const int sI_in[2]  = {2, 4};
    const int sI_nd[2]  = {NFc, N0c};
    const int sII_in[14] = {6, 8, 10, 12, 14, 16, 18, 20, 22, 24, 26, 28, 30, 32};
    const int sII_nd[14] = {NCc, N0c, N1c, N2c, N3c, N4c, N1c, N2c, N3c, N4c,
                            N0c, N1c, N2c, N3c};

    // ---- zone sizing (units of 4 B) ----
    size_t sumNdI = 0, sumEI = 0, sumNdII = 0, sumEII = 0;
    for (int t = 0; t < 2;  ++t) { sumNdI  += sI_nd[t];  sumEI  += EN(sI_in[t]); }
    for (int t = 0; t < 14; ++t) { sumNdII += sII_nd[t]; sumEII += EN(sII_in[t]); }
    size_t zI  = pad4(sumNdI  + 1) + pad4(2 * sumEI);
    size_t zII = pad4(sumNdII + 1) + pad4(2 * sumEII);
    size_t zAB = (zI > zII) ? zI : zII;                      // ~25.13M units
    size_t zC_o = zAB, zD_o = zAB + 8000000;
    size_t part_o = zD_o + 18000000;                         // +1024 ints
    // total ~51.13M units ~204.5 MB (R4-proven budget)

    int* part = (int*)(ws + part_o);
    const int B = 256;
    auto G = [&](int n) { return dim3((unsigned)((n + B - 1) / B)); };

    // build temps live in ZoneD (free before h / between h-death and mids)
    int* degB  = (int*)(ws + zD_o);

    // fused per-stage build; fills doff[] (per-set offset into starts array)
    auto buildStage = [&](int ns, const int* sin, const int* snd,
                          int* starts, int2* pool, int* doffOut) {
        size_t sumNd = 0, sumE = 0;
        int eoff[14];
        for (int t = 0; t < ns; ++t) {
            doffOut[t] = (int)sumNd; sumNd += snd[t];
            eoff[t]    = (int)sumE;  sumE  += EN(sin[t]);
        }
        int* rankB = degB + pad4(sumNd);
        hipMemsetAsync(degB, 0, sumNd * 4, stream);
        for (int t = 0; t < ns; ++t) {
            int E = EN(sin[t]);
            hist8_k<<<dim3((unsigned)((E + 2047) / 2048)), B, 0, stream>>>(
                DST(sin[t]), degB + doffOut[t], rankB + eoff[t], E);
        }
        int nb = (int)((sumNd + SCHUNK - 1) / SCHUNK);
        scan1_k<<<dim3((unsigned)nb), B, 0, stream>>>(degB, starts, part, (int)sumNd);
        scan2_k<<<1, 1024, 0, stream>>>(part, nb);
        scan3_k<<<G((int)sumNd + 1), B, 0, stream>>>(starts, part, (int)sumNd, (int)sumE);
        for (int t = 0; t < ns; ++t) {
            int E = EN(sin[t]);
            reorder4_k<<<dim3((unsigned)((E + 1023) / 1024)), B, 0, stream>>>(
                SRC(sin[t]), DST(sin[t]), EA(sin[t]), rankB + eoff[t],
                starts + doffOut[t], pool, E);
        }
    };

    // ---- feature buffers ----
    float* h   = ws + zD_o;                  // [NF,12], steps 1-2
    float* c1  = ws + zC_o;                  // [N0,16], steps 2-19
    float* tpc = c1;                         // steps 20-21 (c1 dead)
    size_t mb = zD_o;
    auto mal = [&](size_t n) { size_t o = mb; mb += pad4(n); return ws + o; };
    float* p1  = mal((size_t)N1c*16);
    float* c2  = mal((size_t)N1c*16);
    float* p2  = mal((size_t)N2c*16);
    float* c3  = mal((size_t)N2c*16);
    float* p3  = mal((size_t)N3c*16);
    float* c4  = mal((size_t)N3c*32);
    float* p4  = mal((size_t)N4c*32);
    float* c5a = mal((size_t)N4c*32);
    float* c5b = mal((size_t)N4c*32);
    float* u3  = mal((size_t)N3c*32);
    float* t6  = mal((size_t)N3c*32);
    float* g6  = mal((size_t)N3c*32);
    float* c6  = mal((size_t)N2c*32);
    float* t7  = mal((size_t)N2c*32);
    float* g7  = mal((size_t)N2c*32);
    float* c7  = mal((size_t)N1c*32);
    float* t8  = mal((size_t)N1c*16);
    float* g8  = mal((size_t)N1c*16);        // ends ~zD_o+17.31M <= +18M
    float* c8  = ws + zD_o;                  // overlay [0,8M): mids dead by 18
    float* t9  = ws + zD_o + 8000000;        // overlay [8M,16M): dead by 19
    float* c9a = ws + zD_o;                  // overlay after c8 dies (19)
    float* out = (float*)d_out;

    // ---- Stage I: cf+fp CSRs (ZoneAB) + steps 1-2 ----
    int* startsI = (int*)(ws + 0);
    int2* poolI  = (int2*)(ws + pad4(sumNdI + 1));
    int doffI[2];
    buildStage(2, sI_in, sI_nd, startsI, poolI, doffI);
    // 1) h = relu(gather(cf, xc) @ W_cf + b_cf)                [NF,12]
    gather_conv_k<2,0,12><<<G(NFc), B, 0, stream>>>(
        xc, nullptr, poolI, startsI + doffI[0], W_cf, b_cf, h, NFc);
    // 2) c1 = relu(gather(fp, h||xf) @ W_fp + b_fp)            [N0,16]
    gather_conv_k<12,4,16><<<G(N0c), B, 0, stream>>>(
        h, xf, poolI, startsI + doffI[1], W_fp, b_fp, c1, N0c);

    // ---- Stage II: 14 remaining CSRs (ZoneAB rebuilt; temps over dead h) --
    int* startsII = (int*)(ws + 0);
    int2* poolII  = (int2*)(ws + pad4(sumNdII + 1));
    int doffII[14];
    buildStage(14, sII_in, sII_nd, startsII, poolII, doffII);
    enum { f_pc, f_pp0, f_pp1, f_pp2, f_pp3, f_pp4, f_po0, f_po1, f_po2, f_po3,
           f_up0, f_up1, f_up2, f_up3 };
    auto st = [&](int t) { return startsII + doffII[t]; };
    int2* ec = poolII;

    // ---- Stage III: pipeline (zero atomics) ----
    // 3) p1 = gather(pool0, c1)
    gather_sw_k<16,false><<<G(N1c), B, 0, stream>>>(c1, ec, st(f_po0), nullptr, p1, N1c);
    // 4) c2 = relu(gather(pp1, p1) @ W2 + b2)
    gather_conv_k<16,0,16><<<G(N1c), B, 0, stream>>>(p1, nullptr, ec, st(f_pp1), W2, b2, c2, N1c);
    // 5) p2
    gather_sw_k<16,false><<<G(N2c), B, 0, stream>>>(c2, ec, st(f_po1), nullptr, p2, N2c);
    // 6) c3
    gather_conv_k<16,0,16><<<G(N2c), B, 0, stream>>>(p2, nullptr, ec, st(f_pp2), W3, b3, c3, N2c);
    // 7) p3
    gather_sw_k<16,false><<<G(N3c), B, 0, stream>>>(c3, ec, st(f_po2), nullptr, p3, N3c);
    // 8) c4 = relu(gather(pp3, p3) @ W4 + b4)                  [N3,32]
    gather_conv_k<16,0,32><<<G(N3c), B, 0, stream>>>(p3, nullptr, ec, st(f_pp3), W4, b4, c4, N3c);
    // 9) p4
    gather_sw_k<32,false><<<G(N4c), B, 0, stream>>>(c4, ec, st(f_po3), nullptr, p4, N4c);
    // 10) c5a
    gather_conv_k<32,0,32><<<G(N4c), B, 0, stream>>>(p4, nullptr, ec, st(f_pp4), W5a, b5a, c5a, N4c);
    // 11) c5b
    gather_conv_k<32,0,32><<<G(N4c), B, 0, stream>>>(c5a, nullptr, ec, st(f_pp4), W5b, b5b, c5b, N4c);
    // 12) u3
    gather_sw_k<32,false><<<G(N3c), B, 0, stream>>>(c5b, ec, st(f_up3), nullptr, u3, N3c);
    // 13) g6: FI=64>FO=32 -> pre-transform then gather+bias+relu
    dense2_k<32,32,32><<<G(N3c), B, 0, stream>>>(u3, c4, W6, t6, N3c);
    gather_sw_k<32,true><<<G(N3c), B, 0, stream>>>(t6, ec, st(f_pp3), b6, g6, N3c);
    // 14) c6
    gather_sw_k<32,false><<<G(N2c), B, 0, stream>>>(g6, ec, st(f_up2), nullptr, c6, N2c);
    // 15) g7 (48->32 pre)
    dense2_k<32,16,32><<<G(N2c), B, 0, stream>>>(c6, c3, W7, t7, N2c);
    gather_sw_k<32,true><<<G(N2c), B, 0, stream>>>(t7, ec, st(f_pp2), b7, g7, N2c);
    // 16) c7
    gather_sw_k<32,false><<<G(N1c), B, 0, stream>>>(g7, ec, st(f_up1), nullptr, c7, N1c);
    // 17) g8 (48->16 pre)
    dense2_k<32,16,16><<<G(N1c), B, 0, stream>>>(c7, c2, W8, t8, N1c);
    gather_sw_k<16,true><<<G(N1c), B, 0, stream>>>(t8, ec, st(f_pp1), b8, g8, N1c);
    // 18) c8 = gather(unpool0, g8)   [N0,16] -> ZoneD[0,8M)
    gather_sw_k<16,false><<<G(N0c), B, 0, stream>>>(g8, ec, st(f_up0), nullptr, c8, N0c);
    // 19) c9a (32->16 pre): t9 in ZoneD[8M,16M), c9a overlays c8
    dense2_k<16,16,16><<<G(N0c), B, 0, stream>>>(c8, c1, W9a, t9, N0c);
    gather_sw_k<16,true><<<G(N0c), B, 0, stream>>>(t9, ec, st(f_pp0), b9a, c9a, N0c);
    // 20) pc conv pre-transform (N0 < NC); tpc overlays c1
    dense2_k<16,0,16><<<G(N0c), B, 0, stream>>>(c9a, nullptr, W9b, tpc, N0c);
    // 21) fused pc gather + bias + relu + Wf dot
    gather_final_k<<<G(NCc), B, 0, stream>>>(tpc, ec, st(f_pc), b9b, Wf, bfb, out, NCc);
}